// Round 1
// baseline (354.672 us; speedup 1.0000x reference)
//
#include <hip/hip_runtime.h>
#include <stdint.h>

// SpatialGraphConv fused: 1x1 conv (192x64 GEMM) -> graph matmul (K=75) -> BN.
// B=64, C_in=64, T=300, V=25, K=3, C_out=64.  All MFMA bf16 16x16x32, fp32 acc.
//
// v2: no xT LDS staging.  Stage-1 B-fragments are loaded straight from global
// (per-j coalesced dword loads + v_cvt_pk_bf16_f32 packing) since the x tile
// has zero cross-block reuse.  TT=3 -> Ylds 36KB + Acat 6KB = 42KB LDS,
// 3 blocks/CU.  Only the kv-pad slabs of Ylds are zeroed.

#define TT 3            // t per block
#define NPIX (TT * 25)  // 75 pixels per tile
#define NT1 5           // ceil(80/16) n-tiles for stage 1 (cols 75..79 pad)
#define NBLK 6400       // 64 b * 100 t-tiles

typedef short bf16x8 __attribute__((ext_vector_type(8)));
typedef float f32x4 __attribute__((ext_vector_type(4)));

union frag_u { bf16x8 v; uint32_t u[4]; };

__device__ inline short f2bf(float f) {
    union { float f; uint32_t u; } v; v.f = f;
    uint32_t u = v.u;
    u += 0x7fffu + ((u >> 16) & 1u);   // RNE
    return (short)(u >> 16);
}

__device__ inline uint32_t cvtpk(float lo, float hi) {
    uint32_t d;
    asm("v_cvt_pk_bf16_f32 %0, %1, %2" : "=v"(d) : "v"(lo), "v"(hi));
    return d;
}

__global__ __launch_bounds__(256, 3) void sgc_main(
    const float* __restrict__ x, const float* __restrict__ W,
    const float* __restrict__ bias, const float* __restrict__ A,
    float* __restrict__ out, float* __restrict__ stats_part)
{
    // fragment-linear LDS (chunk addr = tile*1024B + lane*16B)
    __shared__ __align__(16) short Ylds[18432];  // 3 t * 4 cq * 3 k * 64 * 8
    __shared__ __align__(16) short Acat[3072];   // (kb2*2+nt2) * 64 * 8

    const int tid  = threadIdx.x;
    const int lane = tid & 63;
    const int wave = tid >> 6;
    const int q4   = lane >> 4;
    const int wl   = lane & 15;
    const int bid  = blockIdx.x;
    const int b    = bid / 100;
    const int t0   = (bid % 100) * TT;

    // ---- zero only the kv-pad slabs of Ylds (oct 3 of each of 36 tiles) ----
    {
        bf16x8 z8 = {0,0,0,0,0,0,0,0};
        #pragma unroll
        for (int j = 0; j < 3; ++j) {
            int s = tid + 256 * j;
            if (s < 576)
                *(bf16x8*)&Ylds[(s >> 4) * 512 + 384 + (s & 15) * 8] = z8;
        }
    }

    // ---- Acat fragment table: granule g = (kb2*2+nt2)*64 + oct*16 + w15 ----
    #pragma unroll
    for (int j = 0; j < 2; ++j) {
        int g = tid + 256 * j;
        if (g < 384) {
            int tile = g >> 6;
            int kb2  = tile >> 1, nt2 = tile & 1;
            int oct  = (g >> 4) & 3;
            int w    = nt2 * 16 + (g & 15);
            frag_u fr;
            #pragma unroll
            for (int p = 0; p < 4; ++p) {
                int v0 = oct * 8 + 2 * p;
                float a0 = (w < 25 && v0     < 25) ? A[(kb2 * 25 + v0) * 25 + w]     : 0.f;
                float a1 = (w < 25 && v0 + 1 < 25) ? A[(kb2 * 25 + v0 + 1) * 25 + w] : 0.f;
                fr.u[p] = cvtpk(a0, a1);
            }
            *(bf16x8*)&Acat[g * 8] = fr.v;
        }
    }

    // ---- W A-frags straight from global (L2-resident, 49 KB total) ----
    bf16x8 wfrag[3][2];
    #pragma unroll
    for (int mti = 0; mti < 3; ++mti) {
        int o = (wave * 3 + mti) * 16 + wl;
        #pragma unroll
        for (int kb = 0; kb < 2; ++kb) {
            int ci0 = kb * 32 + q4 * 8;
            const float4 f0 = *(const float4*)&W[o * 64 + ci0];
            const float4 f1 = *(const float4*)&W[o * 64 + ci0 + 4];
            frag_u fr;
            fr.u[0] = cvtpk(f0.x, f0.y);
            fr.u[1] = cvtpk(f0.z, f0.w);
            fr.u[2] = cvtpk(f1.x, f1.y);
            fr.u[3] = cvtpk(f1.z, f1.w);
            wfrag[mti][kb] = fr.v;
        }
    }

    // ---- stage 1: Y(192 x 75) = W(192x64) @ x(64x75), fragments from global.
    // B-frag lane l, elem j: ci = kb*32 + (l>>4)*8 + j, n = nt*16 + (l&15).
    // For fixed j the load is coalesced across lanes (n contiguous).
    const float* xp = x + (size_t)b * 480000 + (size_t)t0 * 25;
    f32x4 acc[3][NT1];
    #pragma unroll
    for (int mti = 0; mti < 3; ++mti)
        #pragma unroll
        for (int nt = 0; nt < NT1; ++nt) {
            f32x4 zf = {0.f, 0.f, 0.f, 0.f};
            acc[mti][nt] = zf;
        }

    #pragma unroll
    for (int nt = 0; nt < NT1; ++nt) {
        int n = nt * 16 + wl;
        if (n > NPIX - 1) n = NPIX - 1;       // clamp pad cols (discarded later)
        int loff = q4 * 60000 + n;            // per-lane row+pixel offset
        bf16x8 xb[2];
        #pragma unroll
        for (int kb = 0; kb < 2; ++kb) {
            float xv[8];
            #pragma unroll
            for (int jj = 0; jj < 8; ++jj)
                xv[jj] = (xp + (kb * 32 + jj) * 7500)[loff];  // SGPR base + VGPR off
            frag_u fr;
            #pragma unroll
            for (int p = 0; p < 4; ++p)
                fr.u[p] = cvtpk(xv[2 * p], xv[2 * p + 1]);
            xb[kb] = fr.v;
        }
        #pragma unroll
        for (int mti = 0; mti < 3; ++mti) {
            acc[mti][nt] = __builtin_amdgcn_mfma_f32_16x16x32_bf16(
                wfrag[mti][0], xb[0], acc[mti][nt], 0, 0, 0);
            acc[mti][nt] = __builtin_amdgcn_mfma_f32_16x16x32_bf16(
                wfrag[mti][1], xb[1], acc[mti][nt], 0, 0, 0);
        }
    }

    // bias per (mti, r):  o = (wave*3+mti)*16 + q4*4 + r   (vectorized float4)
    float4 bv[3];
    #pragma unroll
    for (int mti = 0; mti < 3; ++mti)
        bv[mti] = *(const float4*)&bias[(wave * 3 + mti) * 16 + q4 * 4];

    __syncthreads();   // pad-zero & (ordering for) Acat done before writes/reads

    // ---- epilogue: Y + bias -> Ylds (bf16, fragment-linear for stage-2 A) ----
    #pragma unroll
    for (int nt = 0; nt < NT1; ++nt) {
        int n = nt * 16 + wl;
        if (n < NPIX) {
            int t = n / 25, v = n % 25;
            #pragma unroll
            for (int mti = 0; mti < 3; ++mti) {
                int wt = wave * 3 + mti;
                int k  = wt >> 2, cq = wt & 3;
                int kv = k * 32 + v;
                int sbase = ((t * 4 + cq) * 3 + k) * 512
                          + ((kv >> 3) & 3) * 128 + q4 * 32 + (kv & 7);
                const float* bp = (const float*)&bv[mti];
                #pragma unroll
                for (int r = 0; r < 4; ++r)
                    Ylds[sbase + r * 8] = f2bf(acc[mti][nt][r] + bp[r]);
            }
        }
    }
    __syncthreads();

    // ---- stage 2: out_t(64x25) = Yt(64x96) @ Acat(96x25), per t ----
    bf16x8 bfrag2[2][3];
    #pragma unroll
    for (int nt2 = 0; nt2 < 2; ++nt2)
        #pragma unroll
        for (int kb2 = 0; kb2 < 3; ++kb2)
            bfrag2[nt2][kb2] = *(const bf16x8*)&Acat[((kb2 * 2 + nt2) * 64 + lane) * 8];

    float ssum[4] = {0.f, 0.f, 0.f, 0.f};
    float ssq[4]  = {0.f, 0.f, 0.f, 0.f};
    const int c0 = wave * 16 + q4 * 4;

    #pragma unroll
    for (int t = 0; t < TT; ++t) {
        bf16x8 a2[3];
        #pragma unroll
        for (int kb2 = 0; kb2 < 3; ++kb2)
            a2[kb2] = *(const bf16x8*)&Ylds[(((t * 4 + wave) * 3 + kb2) * 64 + lane) * 8];

        f32x4 acc2[2];
        #pragma unroll
        for (int nt2 = 0; nt2 < 2; ++nt2) {
            f32x4 zf = {0.f, 0.f, 0.f, 0.f};
            acc2[nt2] = zf;
            #pragma unroll
            for (int kb2 = 0; kb2 < 3; ++kb2)
                acc2[nt2] = __builtin_amdgcn_mfma_f32_16x16x32_bf16(
                    a2[kb2], bfrag2[nt2][kb2], acc2[nt2], 0, 0, 0);
        }

        #pragma unroll
        for (int nt2 = 0; nt2 < 2; ++nt2) {
            int w = nt2 * 16 + wl;
            bool valid = (w < 25);
            #pragma unroll
            for (int r = 0; r < 4; ++r) {
                float val = acc2[nt2][r];
                if (valid) {
                    out[(size_t)((b * 64 + c0 + r) * 300 + t0 + t) * 25 + w] = val;
                    ssum[r] += val;
                    ssq[r]  += val * val;
                }
            }
        }
    }

    // ---- per-channel partial stats: reduce over the 16 w-lanes ----
    #pragma unroll
    for (int r = 0; r < 4; ++r) {
        float s = ssum[r], q = ssq[r];
        #pragma unroll
        for (int d = 1; d < 16; d <<= 1) {
            s += __shfl_xor(s, d);
            q += __shfl_xor(q, d);
        }
        if (wl == 0) {
            int c = c0 + r;
            int slot = bid & 63;
            atomicAdd(&stats_part[slot * 128 + c], s);
            atomicAdd(&stats_part[slot * 128 + 64 + c], q);
        }
    }
}

__global__ void sgc_finalize(const float* __restrict__ stats_part,
                             const float* __restrict__ gamma,
                             const float* __restrict__ beta,
                             float* __restrict__ scaleshift)
{
    int c = threadIdx.x;  // 64 threads
    float s = 0.f, q = 0.f;
    #pragma unroll 8
    for (int slot = 0; slot < 64; ++slot) {
        s += stats_part[slot * 128 + c];
        q += stats_part[slot * 128 + 64 + c];
    }
    const float invN = 1.f / 480000.f;
    float mean = s * invN;
    float var  = q * invN - mean * mean;
    float rstd = rsqrtf(var + 1e-5f);
    float sc = rstd * gamma[c];
    scaleshift[c]      = sc;
    scaleshift[64 + c] = beta[c] - mean * sc;
}

__global__ __launch_bounds__(256) void sgc_norm(float* __restrict__ out,
                                                const float* __restrict__ scaleshift)
{
    const int total4 = 30720000 / 4;
    int stride = gridDim.x * 256;
    for (int i = blockIdx.x * 256 + threadIdx.x; i < total4; i += stride) {
        int c = (i / 1875) & 63;   // 7500 floats per (b,c) row; /4 = 1875 quads
        float sc = scaleshift[c], sh = scaleshift[64 + c];
        float4 v = *((float4*)out + i);
        v.x = v.x * sc + sh;
        v.y = v.y * sc + sh;
        v.z = v.z * sc + sh;
        v.w = v.w * sc + sh;
        *((float4*)out + i) = v;
    }
}

extern "C" void kernel_launch(void* const* d_in, const int* in_sizes, int n_in,
                              void* d_out, int out_size, void* d_ws, size_t ws_size,
                              hipStream_t stream)
{
    const float* x     = (const float*)d_in[0];
    const float* W     = (const float*)d_in[1];
    const float* bias  = (const float*)d_in[2];
    const float* A     = (const float*)d_in[3];
    const float* gamma = (const float*)d_in[4];
    const float* beta  = (const float*)d_in[5];
    float* out = (float*)d_out;

    float* stats      = (float*)d_ws;        // 64 slots * 128 floats = 32 KB
    float* scaleshift = stats + 64 * 128;    // 128 floats

    hipMemsetAsync(stats, 0, 64 * 128 * sizeof(float), stream);
    sgc_main<<<NBLK, 256, 0, stream>>>(x, W, bias, A, out, stats);
    sgc_finalize<<<1, 64, 0, stream>>>(stats, gamma, beta, scaleshift);
    sgc_norm<<<4096, 256, 0, stream>>>(out, scaleshift);
}